// Round 2
// baseline (809.379 us; speedup 1.0000x reference)
//
#include <hip/hip_runtime.h>

#define NTOK 1024
#define HDIM 2880
#define IDIM 2880
#define NEXP 8

typedef __attribute__((ext_vector_type(4))) float fx4;
typedef __attribute__((ext_vector_type(8))) short sx8;
typedef __attribute__((ext_vector_type(4))) unsigned int uix4;
typedef __attribute__((ext_vector_type(4))) unsigned short usx4;

__device__ __forceinline__ unsigned short f2bf(float f) {
  unsigned u = __builtin_bit_cast(unsigned, f);
  u += 0x7fffu + ((u >> 16) & 1u);
  return (unsigned short)(u >> 16);
}

__global__ __launch_bounds__(256) void init_out_k(const float* __restrict__ x,
                                                  float* __restrict__ out) {
  int i = blockIdx.x * 256 + threadIdx.x;
  ((fx4*)out)[i] = ((const fx4*)x)[i];
}

__global__ __launch_bounds__(256) void rms_router_k(
    const float* __restrict__ x, const float* __restrict__ norm_w,
    const float* __restrict__ gate_w, const float* __restrict__ gate_b,
    unsigned short* __restrict__ t_bf, int* __restrict__ cnt,
    int* __restrict__ tok, float* __restrict__ wgt) {
  const int n = blockIdx.x;
  const int tid = threadIdx.x;
  const int wid = tid >> 6, lane = tid & 63;
  const float* xr = x + (size_t)n * HDIM;

  // pass 1: sum of squares
  float ss = 0.f;
  for (int h = tid; h < HDIM; h += 256) { float v = xr[h]; ss += v * v; }
  #pragma unroll
  for (int o = 32; o > 0; o >>= 1) ss += __shfl_down(ss, o);
  __shared__ float sred[4];
  if (lane == 0) sred[wid] = ss;
  __syncthreads();
  const float rstd =
      rsqrtf((sred[0] + sred[1] + sred[2] + sred[3]) * (1.0f / HDIM) + 1e-5f);

  // pass 2: write t (bf16) and accumulate router logit partials (fp32)
  float p[NEXP];
  #pragma unroll
  for (int e = 0; e < NEXP; e++) p[e] = 0.f;
  for (int h = tid; h < HDIM; h += 256) {
    float xv = xr[h] * norm_w[h];
    t_bf[(size_t)n * HDIM + h] = f2bf(xv * rstd);
    #pragma unroll
    for (int e = 0; e < NEXP; e++) p[e] += xv * gate_w[e * HDIM + h];
  }
  __shared__ float pls[4][NEXP];
  #pragma unroll
  for (int e = 0; e < NEXP; e++) {
    float v = p[e];
    #pragma unroll
    for (int o = 32; o > 0; o >>= 1) v += __shfl_down(v, o);
    if (lane == 0) pls[wid][e] = v;
  }
  __syncthreads();
  if (tid == 0) {
    float lg[NEXP];
    #pragma unroll
    for (int e = 0; e < NEXP; e++)
      lg[e] = (pls[0][e] + pls[1][e] + pls[2][e] + pls[3][e]) * rstd + gate_b[e];
    // top-4, jax tie-breaking (strict >, ascending scan -> lowest index wins)
    unsigned used = 0;
    float val[4];
    int idx[4];
    for (int k = 0; k < 4; k++) {
      float best = -1e30f;
      int bi = 0;
      for (int e = 0; e < NEXP; e++)
        if (!((used >> e) & 1u) && lg[e] > best) { best = lg[e]; bi = e; }
      used |= 1u << bi;
      val[k] = best;
      idx[k] = bi;
    }
    float sum = 0.f, w[4];
    for (int k = 0; k < 4; k++) { w[k] = expf(val[k] - val[0]); sum += w[k]; }
    for (int k = 0; k < 4; k++) {
      int e = idx[k];
      int slot = atomicAdd(&cnt[e], 1);
      tok[e * NTOK + slot] = n;
      wgt[e * NTOK + slot] = w[k] / sum;
    }
  }
}

// GEMM1: act[e,slot,0:I] = glu( t[tok] @ Wgu[e,0:I]^T + b0 ,
//                               t[tok] @ Wgu[e,I:2I]^T + b1 )
// tile: 128 rows (tokens) x 96 cols (I), BK=32, 4 waves (2x2), 16x16x32 bf16
__global__ __launch_bounds__(256) void gemm1_k(
    const unsigned short* __restrict__ t_bf,
    const float* __restrict__ w_gate_up, const float* __restrict__ b_gate_up,
    const int* __restrict__ cnt, const int* __restrict__ tok,
    unsigned short* __restrict__ act_bf) {
  const int e = blockIdx.z;
  const int ce = cnt[e];
  const int m0 = blockIdx.y * 128;
  if (m0 >= ce) return;
  const int c0 = blockIdx.x * 96;
  const int tid = threadIdx.x, lane = tid & 63, wid = tid >> 6;

  __shared__ unsigned short Ash[128 * 40];   // [row][k] pad 40 to dodge conflicts
  __shared__ unsigned short B0sh[96 * 40];   // [col][k]
  __shared__ unsigned short B1sh[96 * 40];

  const fx4 FZ = {0.f, 0.f, 0.f, 0.f};
  fx4 accG[4][3], accL[4][3];
  #pragma unroll
  for (int m = 0; m < 4; m++)
    #pragma unroll
    for (int n = 0; n < 3; n++) { accG[m][n] = FZ; accL[m][n] = FZ; }

  // A staging: 128 rows x 32 bf16 per K-step = 16 shorts per thread
  const int arow = tid >> 1, ajo = (tid & 1) * 16;
  int aslot = m0 + arow;
  if (aslot > ce - 1) aslot = ce - 1;  // clamp; garbage rows guarded at write
  const unsigned short* asrc =
      t_bf + (size_t)tok[e * NTOK + aslot] * HDIM + ajo;
  const float* wb = w_gate_up + (size_t)e * (2 * IDIM) * HDIM;

  const int wm0 = (wid >> 1) * 64, wc0 = (wid & 1) * 48;
  const int fr = lane & 15, fq = lane >> 4;

  for (int k0 = 0; k0 < HDIM; k0 += 32) {
    __syncthreads();
    // stage A: two 16B stores cover the full 32-short row per thread pair
    *(uix4*)&Ash[arow * 40 + ajo] = *(const uix4*)(asrc + k0);
    *(uix4*)&Ash[arow * 40 + ajo + 8] = *(const uix4*)(asrc + k0 + 8);
    // stage B halves: 96x32 fp32 -> bf16
    #pragma unroll
    for (int i = 0; i < 3; i++) {
      int cid = tid + 256 * i;
      int brow = cid >> 3, bko = (cid & 7) * 4;
      const float* s0 = wb + (size_t)(c0 + brow) * HDIM + k0 + bko;
      const float* s1 = wb + (size_t)(IDIM + c0 + brow) * HDIM + k0 + bko;
      fx4 v0 = *(const fx4*)s0;
      fx4 v1 = *(const fx4*)s1;
      usx4 u0 = {f2bf(v0.x), f2bf(v0.y), f2bf(v0.z), f2bf(v0.w)};
      usx4 u1 = {f2bf(v1.x), f2bf(v1.y), f2bf(v1.z), f2bf(v1.w)};
      *(usx4*)&B0sh[brow * 40 + bko] = u0;
      *(usx4*)&B1sh[brow * 40 + bko] = u1;
    }
    __syncthreads();
    sx8 aF[4];
    #pragma unroll
    for (int m = 0; m < 4; m++)
      aF[m] = *(const sx8*)&Ash[(wm0 + m * 16 + fr) * 40 + fq * 8];
    #pragma unroll
    for (int n = 0; n < 3; n++) {
      sx8 b0 = *(const sx8*)&B0sh[(wc0 + n * 16 + fr) * 40 + fq * 8];
      sx8 b1 = *(const sx8*)&B1sh[(wc0 + n * 16 + fr) * 40 + fq * 8];
      #pragma unroll
      for (int m = 0; m < 4; m++) {
        accG[m][n] =
            __builtin_amdgcn_mfma_f32_16x16x32_bf16(aF[m], b0, accG[m][n], 0, 0, 0);
        accL[m][n] =
            __builtin_amdgcn_mfma_f32_16x16x32_bf16(aF[m], b1, accL[m][n], 0, 0, 0);
      }
    }
  }
  // epilogue: bias + GLU, write act_bf
  #pragma unroll
  for (int n = 0; n < 3; n++) {
    const int col = c0 + wc0 + n * 16 + fr;
    const float bg = b_gate_up[e * (2 * IDIM) + col];
    const float bl = b_gate_up[e * (2 * IDIM) + IDIM + col];
    #pragma unroll
    for (int m = 0; m < 4; m++) {
      #pragma unroll
      for (int r = 0; r < 4; r++) {
        int slot = m0 + wm0 + m * 16 + fq * 4 + r;
        if (slot < ce) {
          float g = accG[m][n][r] + bg;
          float l = accL[m][n][r] + bl;
          float a = g * (1.0f / (1.0f + __expf(-1.702f * g))) * (l + 1.0f);
          act_bf[((size_t)e * NTOK + slot) * IDIM + col] = f2bf(a);
        }
      }
    }
  }
}

// GEMM2: out[tok,col] += wgt * ( act[e,slot] @ Wd[e,col]^T + b_down[e,col] )
__global__ __launch_bounds__(256) void gemm2_k(
    const unsigned short* __restrict__ act_bf, const float* __restrict__ w_down,
    const float* __restrict__ b_down, const int* __restrict__ cnt,
    const int* __restrict__ tok, const float* __restrict__ wgt,
    float* __restrict__ out) {
  const int e = blockIdx.z;
  const int ce = cnt[e];
  const int m0 = blockIdx.y * 128;
  if (m0 >= ce) return;
  const int c0 = blockIdx.x * 96;
  const int tid = threadIdx.x, lane = tid & 63, wid = tid >> 6;

  __shared__ unsigned short Ash[128 * 40];
  __shared__ unsigned short Bsh[96 * 40];

  const fx4 FZ = {0.f, 0.f, 0.f, 0.f};
  fx4 acc[4][3];
  #pragma unroll
  for (int m = 0; m < 4; m++)
    #pragma unroll
    for (int n = 0; n < 3; n++) acc[m][n] = FZ;

  const int arow = tid >> 1, ajo = (tid & 1) * 16;
  const unsigned short* asrc =
      act_bf + ((size_t)e * NTOK + m0 + arow) * IDIM + ajo;
  const float* wb = w_down + (size_t)e * HDIM * IDIM;

  const int wm0 = (wid >> 1) * 64, wc0 = (wid & 1) * 48;
  const int fr = lane & 15, fq = lane >> 4;

  for (int k0 = 0; k0 < IDIM; k0 += 32) {
    __syncthreads();
    *(uix4*)&Ash[arow * 40 + ajo] = *(const uix4*)(asrc + k0);
    *(uix4*)&Ash[arow * 40 + ajo + 8] = *(const uix4*)(asrc + k0 + 8);
    #pragma unroll
    for (int i = 0; i < 3; i++) {
      int cid = tid + 256 * i;
      int brow = cid >> 3, bko = (cid & 7) * 4;
      const float* s0 = wb + (size_t)(c0 + brow) * IDIM + k0 + bko;
      fx4 v0 = *(const fx4*)s0;
      usx4 u0 = {f2bf(v0.x), f2bf(v0.y), f2bf(v0.z), f2bf(v0.w)};
      *(usx4*)&Bsh[brow * 40 + bko] = u0;
    }
    __syncthreads();
    sx8 aF[4];
    #pragma unroll
    for (int m = 0; m < 4; m++)
      aF[m] = *(const sx8*)&Ash[(wm0 + m * 16 + fr) * 40 + fq * 8];
    #pragma unroll
    for (int n = 0; n < 3; n++) {
      sx8 b0 = *(const sx8*)&Bsh[(wc0 + n * 16 + fr) * 40 + fq * 8];
      #pragma unroll
      for (int m = 0; m < 4; m++)
        acc[m][n] =
            __builtin_amdgcn_mfma_f32_16x16x32_bf16(aF[m], b0, acc[m][n], 0, 0, 0);
    }
  }
  #pragma unroll
  for (int n = 0; n < 3; n++) {
    const int col = c0 + wc0 + n * 16 + fr;
    const float bias = b_down[e * HDIM + col];
    #pragma unroll
    for (int m = 0; m < 4; m++) {
      #pragma unroll
      for (int r = 0; r < 4; r++) {
        int slot = m0 + wm0 + m * 16 + fq * 4 + r;
        if (slot < ce) {
          int token = tok[e * NTOK + slot];
          float w = wgt[e * NTOK + slot];
          atomicAdd(&out[(size_t)token * HDIM + col], w * (acc[m][n][r] + bias));
        }
      }
    }
  }
}

extern "C" void kernel_launch(void* const* d_in, const int* in_sizes, int n_in,
                              void* d_out, int out_size, void* d_ws,
                              size_t ws_size, hipStream_t stream) {
  const float* x = (const float*)d_in[0];
  const float* norm_w = (const float*)d_in[1];
  const float* gate_w = (const float*)d_in[2];
  const float* gate_b = (const float*)d_in[3];
  const float* w_gate_up = (const float*)d_in[4];
  const float* b_gate_up = (const float*)d_in[5];
  const float* w_down = (const float*)d_in[6];
  const float* b_down = (const float*)d_in[7];
  float* out = (float*)d_out;

  char* ws = (char*)d_ws;
  unsigned short* t_bf = (unsigned short*)ws;
  ws += (size_t)NTOK * HDIM * 2;
  unsigned short* act_bf = (unsigned short*)ws;
  ws += (size_t)NEXP * NTOK * IDIM * 2;
  int* cnt = (int*)ws;
  ws += 256;
  int* tok = (int*)ws;
  ws += (size_t)NEXP * NTOK * 4;
  float* wgt = (float*)ws;
  ws += (size_t)NEXP * NTOK * 4;

  hipMemsetAsync(cnt, 0, NEXP * sizeof(int), stream);
  init_out_k<<<2880, 256, 0, stream>>>(x, out);
  rms_router_k<<<NTOK, 256, 0, stream>>>(x, norm_w, gate_w, gate_b, t_bf, cnt,
                                         tok, wgt);
  gemm1_k<<<dim3(30, 8, NEXP), 256, 0, stream>>>(t_bf, w_gate_up, b_gate_up,
                                                 cnt, tok, act_bf);
  gemm2_k<<<dim3(30, 8, NEXP), 256, 0, stream>>>(act_bf, w_down, b_down, cnt,
                                                 tok, wgt, out);
}

// Round 3
// 770.082 us; speedup vs baseline: 1.0510x; 1.0510x over previous
//
#include <hip/hip_runtime.h>

#define NTOK 1024
#define HDIM 2880
#define IDIM 2880
#define NEXP 8
#define BK 32
#define NSTEP (HDIM / BK)  // 90
#define BM 640

typedef __attribute__((ext_vector_type(4))) float fx4;
typedef __attribute__((ext_vector_type(8))) short sx8;
typedef __attribute__((ext_vector_type(4))) unsigned short usx4;

typedef const __attribute__((address_space(1))) void* gas_p;
typedef __attribute__((address_space(3))) void* las_p;

__device__ __forceinline__ unsigned short f2bf(float f) {
  unsigned u = __builtin_bit_cast(unsigned, f);
  u += 0x7fffu + ((u >> 16) & 1u);
  return (unsigned short)(u >> 16);
}
__device__ __forceinline__ usx4 cvt4(fx4 v) {
  usx4 u = {f2bf(v.x), f2bf(v.y), f2bf(v.z), f2bf(v.w)};
  return u;
}

__global__ __launch_bounds__(256) void init_out_k(const float* __restrict__ x,
                                                  float* __restrict__ out) {
  int i = blockIdx.x * 256 + threadIdx.x;
  ((fx4*)out)[i] = ((const fx4*)x)[i];
}

__global__ __launch_bounds__(256) void rms_router_k(
    const float* __restrict__ x, const float* __restrict__ norm_w,
    const float* __restrict__ gate_w, const float* __restrict__ gate_b,
    unsigned short* __restrict__ t_bf, int* __restrict__ cnt,
    int* __restrict__ tok, float* __restrict__ wgt) {
  const int n = blockIdx.x;
  const int tid = threadIdx.x;
  const int wid = tid >> 6, lane = tid & 63;
  const float* xr = x + (size_t)n * HDIM;

  float ss = 0.f;
  for (int h = tid; h < HDIM; h += 256) { float v = xr[h]; ss += v * v; }
  #pragma unroll
  for (int o = 32; o > 0; o >>= 1) ss += __shfl_down(ss, o);
  __shared__ float sred[4];
  if (lane == 0) sred[wid] = ss;
  __syncthreads();
  const float rstd =
      rsqrtf((sred[0] + sred[1] + sred[2] + sred[3]) * (1.0f / HDIM) + 1e-5f);

  float p[NEXP];
  #pragma unroll
  for (int e = 0; e < NEXP; e++) p[e] = 0.f;
  for (int h = tid; h < HDIM; h += 256) {
    float xv = xr[h] * norm_w[h];
    t_bf[(size_t)n * HDIM + h] = f2bf(xv * rstd);
    #pragma unroll
    for (int e = 0; e < NEXP; e++) p[e] += xv * gate_w[e * HDIM + h];
  }
  __shared__ float pls[4][NEXP];
  #pragma unroll
  for (int e = 0; e < NEXP; e++) {
    float v = p[e];
    #pragma unroll
    for (int o = 32; o > 0; o >>= 1) v += __shfl_down(v, o);
    if (lane == 0) pls[wid][e] = v;
  }
  __syncthreads();
  if (tid == 0) {
    float lg[NEXP];
    #pragma unroll
    for (int e = 0; e < NEXP; e++)
      lg[e] = (pls[0][e] + pls[1][e] + pls[2][e] + pls[3][e]) * rstd + gate_b[e];
    unsigned used = 0;
    float val[4];
    int idx[4];
    for (int k = 0; k < 4; k++) {
      float best = -1e30f;
      int bi = 0;
      for (int e = 0; e < NEXP; e++)
        if (!((used >> e) & 1u) && lg[e] > best) { best = lg[e]; bi = e; }
      used |= 1u << bi;
      val[k] = best;
      idx[k] = bi;
    }
    float sum = 0.f, w[4];
    for (int k = 0; k < 4; k++) { w[k] = expf(val[k] - val[0]); sum += w[k]; }
    for (int k = 0; k < 4; k++) {
      int e = idx[k];
      int slot = atomicAdd(&cnt[e], 1);
      tok[e * NTOK + slot] = n;
      wgt[e * NTOK + slot] = w[k] / sum;
    }
  }
}

// GEMM1: fetch-once. BM=640 x (48 glu + 48 lin cols), BK=32, 8 waves.
__global__ __launch_bounds__(512) void gemm1_k(
    const unsigned short* __restrict__ t_bf,
    const float* __restrict__ w_gate_up, const float* __restrict__ b_gate_up,
    const int* __restrict__ cnt, const int* __restrict__ tok,
    unsigned short* __restrict__ act_bf) {
  const int e = blockIdx.x;
  const int ce = cnt[e];
  const int m0 = blockIdx.z * BM;
  if (m0 >= ce) return;
  const int c0 = blockIdx.y * 48;
  const int tid = threadIdx.x, lane = tid & 63, wid = tid >> 6;
  const int fr = lane & 15, fq = lane >> 4;

  __shared__ unsigned short Ash[2][BM * BK];       // 80 KB, [row][k] linear
  __shared__ unsigned short Bsh[2][2][48 * BK];    // 12 KB, [buf][panel][col*32+k]

  const fx4 FZ = {0.f, 0.f, 0.f, 0.f};
  fx4 accG[5][3], accL[5][3];
  #pragma unroll
  for (int m = 0; m < 5; m++)
    #pragma unroll
    for (int n = 0; n < 3; n++) { accG[m][n] = FZ; accL[m][n] = FZ; }

  // A gather bases (per-lane): instr j stages rows [wid*80+j*16, +16)
  const unsigned short* gA[5];
  #pragma unroll
  for (int j = 0; j < 5; ++j) {
    int row = m0 + wid * 80 + j * 16 + (lane >> 2);
    int rc = row < ce ? row : ce - 1;
    gA[j] = t_bf + (size_t)tok[e * NTOK + rc] * HDIM + (lane & 3) * 8;
  }
  const float* wb = w_gate_up + (size_t)e * (2 * IDIM) * HDIM;
  // B loads: flat f in [0,768); thread covers f=tid and (tid<256) f=tid+512
  const int p0 = tid >= 384, i0 = tid - p0 * 384;
  const int bc0 = i0 >> 3, bk0 = (i0 & 7) * 4;
  const int i1 = tid + 128;  // panel 1 (only tid<256)
  const int bc1 = i1 >> 3, bk1 = (i1 & 7) * 4;
  const float* srcB0 = wb + (size_t)(p0 * IDIM + c0 + bc0) * HDIM + bk0;
  const float* srcB1 = wb + (size_t)(IDIM + c0 + bc1) * HDIM + bk1;

  fx4 rB0, rB1;
  #define G1_STAGE_ISSUE(buf, k0)                                              \
    {                                                                          \
      _Pragma("unroll") for (int j = 0; j < 5; ++j)                            \
          __builtin_amdgcn_global_load_lds(                                    \
              (gas_p)(gA[j] + (k0)),                                           \
              (las_p)&Ash[buf][(wid * 80 + j * 16) * BK], 16, 0, 0);           \
      rB0 = *(const fx4*)(srcB0 + (k0));                                       \
      if (tid < 256) rB1 = *(const fx4*)(srcB1 + (k0));                        \
    }
  #define G1_STAGE_WRITE(buf)                                                  \
    {                                                                          \
      *(usx4*)&Bsh[buf][p0][bc0 * BK + bk0] = cvt4(rB0);                       \
      if (tid < 256) *(usx4*)&Bsh[buf][1][bc1 * BK + bk1] = cvt4(rB1);         \
    }
  #define G1_COMPUTE(buf)                                                      \
    {                                                                          \
      sx8 aF[5];                                                               \
      _Pragma("unroll") for (int m = 0; m < 5; ++m) aF[m] =                    \
          *(const sx8*)&Ash[buf][(wid * 80 + m * 16 + fr) * BK + fq * 8];      \
      _Pragma("unroll") for (int n = 0; n < 3; ++n) {                          \
        sx8 bG = *(const sx8*)&Bsh[buf][0][(n * 16 + fr) * BK + fq * 8];       \
        sx8 bL = *(const sx8*)&Bsh[buf][1][(n * 16 + fr) * BK + fq * 8];       \
        _Pragma("unroll") for (int m = 0; m < 5; ++m) {                        \
          accG[m][n] = __builtin_amdgcn_mfma_f32_16x16x32_bf16(aF[m], bG,      \
                                                               accG[m][n], 0, 0, 0); \
          accL[m][n] = __builtin_amdgcn_mfma_f32_16x16x32_bf16(aF[m], bL,      \
                                                               accL[m][n], 0, 0, 0); \
        }                                                                      \
      }                                                                        \
    }

  G1_STAGE_ISSUE(0, 0);
  asm volatile("s_waitcnt vmcnt(0)" ::: "memory");
  G1_STAGE_WRITE(0);
  __syncthreads();
  for (int s = 0; s < NSTEP - 1; ++s) {
    const int cur = s & 1, nxt = cur ^ 1;
    const int k0 = (s + 1) * BK;
    G1_STAGE_ISSUE(nxt, k0);
    G1_COMPUTE(cur);
    asm volatile("s_waitcnt vmcnt(0)" ::: "memory");
    G1_STAGE_WRITE(nxt);
    __syncthreads();
  }
  G1_COMPUTE((NSTEP - 1) & 1);

  // epilogue: bias + GLU -> act_bf
  #pragma unroll
  for (int n = 0; n < 3; ++n) {
    const int col = c0 + n * 16 + fr;
    const float bg = b_gate_up[e * (2 * IDIM) + col];
    const float bl = b_gate_up[e * (2 * IDIM) + IDIM + col];
    #pragma unroll
    for (int m = 0; m < 5; ++m) {
      #pragma unroll
      for (int r = 0; r < 4; ++r) {
        int slot = m0 + wid * 80 + m * 16 + fq * 4 + r;
        if (slot < ce) {
          float g = accG[m][n][r] + bg;
          float l = accL[m][n][r] + bl;
          float a = g * (1.0f / (1.0f + __expf(-1.702f * g))) * (l + 1.0f);
          act_bf[((size_t)e * NTOK + slot) * IDIM + col] = f2bf(a);
        }
      }
    }
  }
}

// GEMM2: fetch-once. BM=640 x 64 cols, BK=32, 8 waves.
__global__ __launch_bounds__(512) void gemm2_k(
    const unsigned short* __restrict__ act_bf, const float* __restrict__ w_down,
    const float* __restrict__ b_down, const int* __restrict__ cnt,
    const int* __restrict__ tok, const float* __restrict__ wgt,
    float* __restrict__ out) {
  const int e = blockIdx.x;
  const int ce = cnt[e];
  const int m0 = blockIdx.z * BM;
  if (m0 >= ce) return;
  const int c0 = blockIdx.y * 64;
  const int tid = threadIdx.x, lane = tid & 63, wid = tid >> 6;
  const int fr = lane & 15, fq = lane >> 4;

  __shared__ unsigned short Ash[2][BM * BK];     // 80 KB
  __shared__ unsigned short Bsh[2][64 * BK];     // 8 KB

  const fx4 FZ = {0.f, 0.f, 0.f, 0.f};
  fx4 acc[5][4];
  #pragma unroll
  for (int m = 0; m < 5; m++)
    #pragma unroll
    for (int n = 0; n < 4; n++) acc[m][n] = FZ;

  const unsigned short* gA[5];
  #pragma unroll
  for (int j = 0; j < 5; ++j) {
    int row = m0 + wid * 80 + j * 16 + (lane >> 2);
    int rc = row < NTOK ? row : NTOK - 1;
    gA[j] = act_bf + ((size_t)e * NTOK + rc) * IDIM + (lane & 3) * 8;
  }
  const float* wb = w_down + (size_t)e * HDIM * IDIM;
  const int bc = tid >> 3, bk = (tid & 7) * 4;   // 64 cols x 8 fx4-chunks
  const float* srcB = wb + (size_t)(c0 + bc) * IDIM + bk;

  fx4 rB;
  #define G2_STAGE_ISSUE(buf, k0)                                              \
    {                                                                          \
      _Pragma("unroll") for (int j = 0; j < 5; ++j)                            \
          __builtin_amdgcn_global_load_lds(                                    \
              (gas_p)(gA[j] + (k0)),                                           \
              (las_p)&Ash[buf][(wid * 80 + j * 16) * BK], 16, 0, 0);           \
      rB = *(const fx4*)(srcB + (k0));                                         \
    }
  #define G2_STAGE_WRITE(buf) { *(usx4*)&Bsh[buf][bc * BK + bk] = cvt4(rB); }
  #define G2_COMPUTE(buf)                                                      \
    {                                                                          \
      sx8 aF[5];                                                               \
      _Pragma("unroll") for (int m = 0; m < 5; ++m) aF[m] =                    \
          *(const sx8*)&Ash[buf][(wid * 80 + m * 16 + fr) * BK + fq * 8];      \
      _Pragma("unroll") for (int n = 0; n < 4; ++n) {                          \
        sx8 b0 = *(const sx8*)&Bsh[buf][(n * 16 + fr) * BK + fq * 8];          \
        _Pragma("unroll") for (int m = 0; m < 5; ++m)                          \
            acc[m][n] = __builtin_amdgcn_mfma_f32_16x16x32_bf16(aF[m], b0,     \
                                                                acc[m][n], 0, 0, 0); \
      }                                                                        \
    }

  G2_STAGE_ISSUE(0, 0);
  asm volatile("s_waitcnt vmcnt(0)" ::: "memory");
  G2_STAGE_WRITE(0);
  __syncthreads();
  for (int s = 0; s < NSTEP - 1; ++s) {
    const int cur = s & 1, nxt = cur ^ 1;
    const int k0 = (s + 1) * BK;
    G2_STAGE_ISSUE(nxt, k0);
    G2_COMPUTE(cur);
    asm volatile("s_waitcnt vmcnt(0)" ::: "memory");
    G2_STAGE_WRITE(nxt);
    __syncthreads();
  }
  G2_COMPUTE((NSTEP - 1) & 1);

  #pragma unroll
  for (int n = 0; n < 4; ++n) {
    const int col = c0 + n * 16 + fr;
    const float bias = b_down[e * HDIM + col];
    #pragma unroll
    for (int m = 0; m < 5; ++m) {
      #pragma unroll
      for (int r = 0; r < 4; ++r) {
        int slot = m0 + wid * 80 + m * 16 + fq * 4 + r;
        if (slot < ce) {
          int token = tok[e * NTOK + slot];
          float w = wgt[e * NTOK + slot];
          atomicAdd(&out[(size_t)token * HDIM + col], w * (acc[m][n][r] + bias));
        }
      }
    }
  }
}

extern "C" void kernel_launch(void* const* d_in, const int* in_sizes, int n_in,
                              void* d_out, int out_size, void* d_ws,
                              size_t ws_size, hipStream_t stream) {
  const float* x = (const float*)d_in[0];
  const float* norm_w = (const float*)d_in[1];
  const float* gate_w = (const float*)d_in[2];
  const float* gate_b = (const float*)d_in[3];
  const float* w_gate_up = (const float*)d_in[4];
  const float* b_gate_up = (const float*)d_in[5];
  const float* w_down = (const float*)d_in[6];
  const float* b_down = (const float*)d_in[7];
  float* out = (float*)d_out;

  char* ws = (char*)d_ws;
  unsigned short* t_bf = (unsigned short*)ws;
  ws += (size_t)NTOK * HDIM * 2;
  unsigned short* act_bf = (unsigned short*)ws;
  ws += (size_t)NEXP * NTOK * IDIM * 2;
  int* cnt = (int*)ws;
  ws += 256;
  int* tok = (int*)ws;
  ws += (size_t)NEXP * NTOK * 4;
  float* wgt = (float*)ws;
  ws += (size_t)NEXP * NTOK * 4;

  hipMemsetAsync(cnt, 0, NEXP * sizeof(int), stream);
  init_out_k<<<2880, 256, 0, stream>>>(x, out);
  rms_router_k<<<NTOK, 256, 0, stream>>>(x, norm_w, gate_w, gate_b, t_bf, cnt,
                                         tok, wgt);
  // expert = blockIdx.x (fastest) -> experts round-robin over XCDs;
  // each expert's gathered A panel (~3.7 MB) stays L2-resident per XCD.
  gemm1_k<<<dim3(NEXP, 60, 2), 512, 0, stream>>>(t_bf, w_gate_up, b_gate_up,
                                                 cnt, tok, act_bf);
  gemm2_k<<<dim3(NEXP, 45, 2), 512, 0, stream>>>(act_bf, w_down, b_down, cnt,
                                                 tok, wgt, out);
}

// Round 4
// 711.320 us; speedup vs baseline: 1.1379x; 1.0826x over previous
//
#include <hip/hip_runtime.h>

#define NTOK 1024
#define HDIM 2880
#define IDIM 2880
#define NEXP 8
#define BK 32
#define NSTEP (HDIM / BK)  // 90
#define BM 256

typedef __attribute__((ext_vector_type(4))) float fx4;
typedef __attribute__((ext_vector_type(8))) short sx8;
typedef __attribute__((ext_vector_type(4))) unsigned short usx4;
typedef __attribute__((ext_vector_type(8))) unsigned short usx8;

typedef const __attribute__((address_space(1))) void* gas_p;
typedef __attribute__((address_space(3))) void* las_p;

__device__ __forceinline__ unsigned short f2bf(float f) {
  unsigned u = __builtin_bit_cast(unsigned, f);
  u += 0x7fffu + ((u >> 16) & 1u);
  return (unsigned short)(u >> 16);
}
__device__ __forceinline__ usx4 cvt4(fx4 v) {
  usx4 u = {f2bf(v.x), f2bf(v.y), f2bf(v.z), f2bf(v.w)};
  return u;
}
__device__ __forceinline__ usx8 cvt8(fx4 a, fx4 b) {
  usx8 u = {f2bf(a.x), f2bf(a.y), f2bf(a.z), f2bf(a.w),
            f2bf(b.x), f2bf(b.y), f2bf(b.z), f2bf(b.w)};
  return u;
}

__global__ __launch_bounds__(256) void init_out_k(const float* __restrict__ x,
                                                  float* __restrict__ out) {
  int i = blockIdx.x * 256 + threadIdx.x;
  ((fx4*)out)[i] = ((const fx4*)x)[i];
}

__global__ __launch_bounds__(256) void rms_router_k(
    const float* __restrict__ x, const float* __restrict__ norm_w,
    const float* __restrict__ gate_w, const float* __restrict__ gate_b,
    unsigned short* __restrict__ t_bf, int* __restrict__ cnt,
    int* __restrict__ tok, float* __restrict__ wgt) {
  const int n = blockIdx.x;
  const int tid = threadIdx.x;
  const int wid = tid >> 6, lane = tid & 63;
  const float* xr = x + (size_t)n * HDIM;

  float ss = 0.f;
  for (int h = tid; h < HDIM; h += 256) { float v = xr[h]; ss += v * v; }
  #pragma unroll
  for (int o = 32; o > 0; o >>= 1) ss += __shfl_down(ss, o);
  __shared__ float sred[4];
  if (lane == 0) sred[wid] = ss;
  __syncthreads();
  const float rstd =
      rsqrtf((sred[0] + sred[1] + sred[2] + sred[3]) * (1.0f / HDIM) + 1e-5f);

  float p[NEXP];
  #pragma unroll
  for (int e = 0; e < NEXP; e++) p[e] = 0.f;
  for (int h = tid; h < HDIM; h += 256) {
    float xv = xr[h] * norm_w[h];
    t_bf[(size_t)n * HDIM + h] = f2bf(xv * rstd);
    #pragma unroll
    for (int e = 0; e < NEXP; e++) p[e] += xv * gate_w[e * HDIM + h];
  }
  __shared__ float pls[4][NEXP];
  #pragma unroll
  for (int e = 0; e < NEXP; e++) {
    float v = p[e];
    #pragma unroll
    for (int o = 32; o > 0; o >>= 1) v += __shfl_down(v, o);
    if (lane == 0) pls[wid][e] = v;
  }
  __syncthreads();
  if (tid == 0) {
    float lg[NEXP];
    #pragma unroll
    for (int e = 0; e < NEXP; e++)
      lg[e] = (pls[0][e] + pls[1][e] + pls[2][e] + pls[3][e]) * rstd + gate_b[e];
    unsigned used = 0;
    float val[4];
    int idx[4];
    for (int k = 0; k < 4; k++) {
      float best = -1e30f;
      int bi = 0;
      for (int e = 0; e < NEXP; e++)
        if (!((used >> e) & 1u) && lg[e] > best) { best = lg[e]; bi = e; }
      used |= 1u << bi;
      val[k] = best;
      idx[k] = bi;
    }
    float sum = 0.f, w[4];
    for (int k = 0; k < 4; k++) { w[k] = expf(val[k] - val[0]); sum += w[k]; }
    for (int k = 0; k < 4; k++) {
      int e = idx[k];
      int slot = atomicAdd(&cnt[e], 1);
      tok[e * NTOK + slot] = n;
      wgt[e * NTOK + slot] = w[k] / sum;
    }
  }
}

// GEMM1: BM=256 x (64 glu + 64 lin) cols, BK=32, 8 waves (4m x 2n), dbuf.
// A via global_load_lds with XOR-swizzled source chunks; B reg-staged into
// padded LDS. LDS 52 KB -> 2 blocks/CU.
__global__ __launch_bounds__(512) void gemm1_k(
    const unsigned short* __restrict__ t_bf,
    const float* __restrict__ w_gate_up, const float* __restrict__ b_gate_up,
    const int* __restrict__ cnt, const int* __restrict__ tok,
    unsigned short* __restrict__ act_bf) {
  const int e = blockIdx.y;
  const int ce = cnt[e];
  const int m0 = blockIdx.z * BM;
  if (m0 >= ce) return;
  const int c0 = blockIdx.x * 64;
  const int tid = threadIdx.x, lane = tid & 63, wid = tid >> 6;
  const int fr = lane & 15, fq = lane >> 4;
  const int wm = wid >> 1, wn = wid & 1;
  const int achunk = fq ^ ((fr >> 1) & 3);  // A read-side swizzle

  __shared__ unsigned short Ash[2][BM * BK];    // 32 KB, linear (gload_lds)
  __shared__ unsigned short Bsh[2][128 * 40];   // 20 KB, pad 40

  const fx4 FZ = {0.f, 0.f, 0.f, 0.f};
  fx4 accG[4][2], accL[4][2];
  #pragma unroll
  for (int m = 0; m < 4; m++)
    #pragma unroll
    for (int n = 0; n < 2; n++) { accG[m][n] = FZ; accL[m][n] = FZ; }

  // A gather: instr j stages rows [wid*32+j*16, +16); source chunk
  // pre-swizzled so linear LDS write lands XOR-swizzled (m173 pattern).
  const unsigned short* gA[2];
  #pragma unroll
  for (int j = 0; j < 2; ++j) {
    int R = m0 + wid * 32 + j * 16 + (lane >> 2);
    int rc = R < ce ? R : ce - 1;
    gA[j] = t_bf + (size_t)tok[e * NTOK + rc] * HDIM +
            ((lane & 3) ^ ((lane >> 3) & 3)) * 8;
  }
  // B: thread t covers panel row br = t>>2 (0..127: 64 glu + 64 lin),
  // floats [(t&3)*8, +8)
  const int br = tid >> 2, bqf = (tid & 3) * 8;
  const int brow_g = br < 64 ? (c0 + br) : (IDIM + c0 + br - 64);
  const float* srcB =
      w_gate_up + (size_t)e * (2 * IDIM) * HDIM + (size_t)brow_g * HDIM + bqf;

  fx4 rB0, rB1;
  #define G1_ISSUE(buf, k0)                                                    \
    {                                                                          \
      _Pragma("unroll") for (int j = 0; j < 2; ++j)                            \
          __builtin_amdgcn_global_load_lds(                                    \
              (gas_p)(gA[j] + (k0)),                                           \
              (las_p)&Ash[buf][(wid * 32 + j * 16) * BK], 16, 0, 0);           \
      rB0 = *(const fx4*)(srcB + (k0));                                       \
      rB1 = *(const fx4*)(srcB + (k0) + 4);                                   \
    }
  #define G1_WRITE(buf)                                                        \
    { *(usx8*)&Bsh[buf][br * 40 + bqf] = cvt8(rB0, rB1); }
  #define G1_COMPUTE(buf)                                                      \
    {                                                                          \
      sx8 aF[4];                                                               \
      _Pragma("unroll") for (int m = 0; m < 4; ++m) aF[m] =                    \
          *(const sx8*)&Ash[buf][(wm * 64 + m * 16 + fr) * BK + achunk * 8];   \
      _Pragma("unroll") for (int n = 0; n < 2; ++n) {                          \
        sx8 bG = *(const sx8*)&Bsh[buf][(wn * 32 + n * 16 + fr) * 40 + fq * 8];\
        sx8 bL =                                                               \
            *(const sx8*)&Bsh[buf][(64 + wn * 32 + n * 16 + fr) * 40 + fq * 8];\
        _Pragma("unroll") for (int m = 0; m < 4; ++m) {                        \
          accG[m][n] = __builtin_amdgcn_mfma_f32_16x16x32_bf16(aF[m], bG,      \
                                                               accG[m][n], 0, 0, 0); \
          accL[m][n] = __builtin_amdgcn_mfma_f32_16x16x32_bf16(aF[m], bL,      \
                                                               accL[m][n], 0, 0, 0); \
        }                                                                      \
      }                                                                        \
    }

  G1_ISSUE(0, 0);
  asm volatile("s_waitcnt vmcnt(0)" ::: "memory");
  G1_WRITE(0);
  __syncthreads();
  for (int s = 0; s < NSTEP - 1; ++s) {
    const int cur = s & 1, nxt = cur ^ 1;
    G1_ISSUE(nxt, (s + 1) * BK);
    G1_COMPUTE(cur);
    asm volatile("s_waitcnt vmcnt(0)" ::: "memory");
    G1_WRITE(nxt);
    __syncthreads();
  }
  G1_COMPUTE((NSTEP - 1) & 1);

  #pragma unroll
  for (int n = 0; n < 2; ++n) {
    const int col = c0 + wn * 32 + n * 16 + fr;
    const float bg = b_gate_up[e * (2 * IDIM) + col];
    const float bl = b_gate_up[e * (2 * IDIM) + IDIM + col];
    #pragma unroll
    for (int m = 0; m < 4; ++m) {
      #pragma unroll
      for (int r = 0; r < 4; ++r) {
        int slot = m0 + wm * 64 + m * 16 + fq * 4 + r;
        if (slot < ce) {
          float g = accG[m][n][r] + bg;
          float l = accL[m][n][r] + bl;
          float a = g * (1.0f / (1.0f + __expf(-1.702f * g))) * (l + 1.0f);
          act_bf[((size_t)e * NTOK + slot) * IDIM + col] = f2bf(a);
        }
      }
    }
  }
}

// GEMM2: BM=256 x 64 cols, BK=32, 8 waves (4m x 2n), dbuf. LDS 42 KB.
__global__ __launch_bounds__(512) void gemm2_k(
    const unsigned short* __restrict__ act_bf, const float* __restrict__ w_down,
    const float* __restrict__ b_down, const int* __restrict__ cnt,
    const int* __restrict__ tok, const float* __restrict__ wgt,
    float* __restrict__ out) {
  const int e = blockIdx.y;
  const int ce = cnt[e];
  const int m0 = blockIdx.z * BM;
  if (m0 >= ce) return;
  const int c0 = blockIdx.x * 64;
  const int tid = threadIdx.x, lane = tid & 63, wid = tid >> 6;
  const int fr = lane & 15, fq = lane >> 4;
  const int wm = wid >> 1, wn = wid & 1;
  const int achunk = fq ^ ((fr >> 1) & 3);

  __shared__ unsigned short Ash[2][BM * BK];   // 32 KB
  __shared__ unsigned short Bsh[2][64 * 40];   // 10 KB

  const fx4 FZ = {0.f, 0.f, 0.f, 0.f};
  fx4 acc[4][2];
  #pragma unroll
  for (int m = 0; m < 4; m++)
    #pragma unroll
    for (int n = 0; n < 2; n++) acc[m][n] = FZ;

  const unsigned short* gA[2];
  #pragma unroll
  for (int j = 0; j < 2; ++j) {
    int R = m0 + wid * 32 + j * 16 + (lane >> 2);
    int rc = R < ce ? R : ce - 1;
    gA[j] = act_bf + ((size_t)e * NTOK + rc) * IDIM +
            ((lane & 3) ^ ((lane >> 3) & 3)) * 8;
  }
  // B: 64 rows x 32 floats; thread t: row t>>3, floats [(t&7)*4, +4)
  const int br = tid >> 3, bc4 = (tid & 7) * 4;
  const float* srcB =
      w_down + (size_t)e * HDIM * IDIM + (size_t)(c0 + br) * IDIM + bc4;

  fx4 rB;
  #define G2_ISSUE(buf, k0)                                                    \
    {                                                                          \
      _Pragma("unroll") for (int j = 0; j < 2; ++j)                            \
          __builtin_amdgcn_global_load_lds(                                    \
              (gas_p)(gA[j] + (k0)),                                           \
              (las_p)&Ash[buf][(wid * 32 + j * 16) * BK], 16, 0, 0);           \
      rB = *(const fx4*)(srcB + (k0));                                        \
    }
  #define G2_WRITE(buf) { *(usx4*)&Bsh[buf][br * 40 + bc4] = cvt4(rB); }
  #define G2_COMPUTE(buf)                                                      \
    {                                                                          \
      sx8 aF[4];                                                               \
      _Pragma("unroll") for (int m = 0; m < 4; ++m) aF[m] =                    \
          *(const sx8*)&Ash[buf][(wm * 64 + m * 16 + fr) * BK + achunk * 8];   \
      _Pragma("unroll") for (int n = 0; n < 2; ++n) {                          \
        sx8 b0 = *(const sx8*)&Bsh[buf][(wn * 32 + n * 16 + fr) * 40 + fq * 8];\
        _Pragma("unroll") for (int m = 0; m < 4; ++m)                          \
            acc[m][n] = __builtin_amdgcn_mfma_f32_16x16x32_bf16(aF[m], b0,     \
                                                                acc[m][n], 0, 0, 0); \
      }                                                                        \
    }

  G2_ISSUE(0, 0);
  asm volatile("s_waitcnt vmcnt(0)" ::: "memory");
  G2_WRITE(0);
  __syncthreads();
  for (int s = 0; s < NSTEP - 1; ++s) {
    const int cur = s & 1, nxt = cur ^ 1;
    G2_ISSUE(nxt, (s + 1) * BK);
    G2_COMPUTE(cur);
    asm volatile("s_waitcnt vmcnt(0)" ::: "memory");
    G2_WRITE(nxt);
    __syncthreads();
  }
  G2_COMPUTE((NSTEP - 1) & 1);

  #pragma unroll
  for (int n = 0; n < 2; ++n) {
    const int col = c0 + wn * 32 + n * 16 + fr;
    const float bias = b_down[e * HDIM + col];
    #pragma unroll
    for (int m = 0; m < 4; ++m) {
      #pragma unroll
      for (int r = 0; r < 4; ++r) {
        int slot = m0 + wm * 64 + m * 16 + fq * 4 + r;
        if (slot < ce) {
          int token = tok[e * NTOK + slot];
          float w = wgt[e * NTOK + slot];
          atomicAdd(&out[(size_t)token * HDIM + col], w * (acc[m][n][r] + bias));
        }
      }
    }
  }
}

extern "C" void kernel_launch(void* const* d_in, const int* in_sizes, int n_in,
                              void* d_out, int out_size, void* d_ws,
                              size_t ws_size, hipStream_t stream) {
  const float* x = (const float*)d_in[0];
  const float* norm_w = (const float*)d_in[1];
  const float* gate_w = (const float*)d_in[2];
  const float* gate_b = (const float*)d_in[3];
  const float* w_gate_up = (const float*)d_in[4];
  const float* b_gate_up = (const float*)d_in[5];
  const float* w_down = (const float*)d_in[6];
  const float* b_down = (const float*)d_in[7];
  float* out = (float*)d_out;

  char* ws = (char*)d_ws;
  unsigned short* t_bf = (unsigned short*)ws;
  ws += (size_t)NTOK * HDIM * 2;
  unsigned short* act_bf = (unsigned short*)ws;
  ws += (size_t)NEXP * NTOK * IDIM * 2;
  int* cnt = (int*)ws;
  ws += 256;
  int* tok = (int*)ws;
  ws += (size_t)NEXP * NTOK * 4;
  float* wgt = (float*)ws;
  ws += (size_t)NEXP * NTOK * 4;

  hipMemsetAsync(cnt, 0, NEXP * sizeof(int), stream);
  init_out_k<<<2880, 256, 0, stream>>>(x, out);
  rms_router_k<<<NTOK, 256, 0, stream>>>(x, norm_w, gate_w, gate_b, t_bf, cnt,
                                         tok, wgt);
  // x = col-tile (fastest) -> consecutive blocks stream different weight
  // slices across XCDs; z row-tile twins are near-concurrent -> L2/L3 reuse.
  gemm1_k<<<dim3(45, NEXP, 4), 512, 0, stream>>>(t_bf, w_gate_up, b_gate_up,
                                                 cnt, tok, act_bf);
  gemm2_k<<<dim3(45, NEXP, 4), 512, 0, stream>>>(act_bf, w_down, b_down, cnt,
                                                 tok, wgt, out);
}